// Round 13
// baseline (217.894 us; speedup 1.0000x reference)
//
#include <hip/hip_runtime.h>
#include <hip/hip_bf16.h>

typedef _Float16 half8 __attribute__((ext_vector_type(8)));
typedef _Float16 half4v __attribute__((ext_vector_type(4)));
typedef float floatx4 __attribute__((ext_vector_type(4)));

// Problem constants: B=8, N=1024, D=512, H=8, DH=64
#define BB 8
#define NN 1024
#define DD 512
#define HH 8
#define DHH 64
#define LOG2E 1.4426950408889634f

// hardware 2^x (v_exp_f32)
#define EXP2F(x) __builtin_amdgcn_exp2f(x)

// async global->LDS, 16B per lane, dest = wave-uniform base + lane*16
__device__ __forceinline__ void gload_lds16(const _Float16* g, _Float16* l) {
    __builtin_amdgcn_global_load_lds(
        (const __attribute__((address_space(1))) void*)g,
        (__attribute__((address_space(3))) void*)l, 16, 0, 0);
}

// ---------------- W fp32->fp16 transpose only (round-8 version) ----------------
// 192 blocks: 3 matrices x 64 tiles of 64x64. Wq pre-scaled by log2(e).
__global__ __launch_bounds__(256) void cvt_kernel(const float* __restrict__ Wq,
                                                  const float* __restrict__ Wk,
                                                  const float* __restrict__ Wv,
                                                  _Float16* __restrict__ Wt) {
    __shared__ __align__(16) _Float16 tb[64][72];
    int t = blockIdx.x;                // 0..191
    int tid = threadIdx.x;
    int which = t >> 6;                // /64
    int rem = t & 63;
    int kt = (rem >> 3) * 64, nt = (rem & 7) * 64;
    const float* W = (which == 0) ? Wq : (which == 1) ? Wk : Wv;
    float wscale = (which == 0) ? LOG2E : 1.0f;
    _Float16* Wto = Wt + (size_t)which * DD * DD;
    for (int i = 0; i < 16; i++) {
        int idx = tid + i * 256;
        int r = idx >> 6, c = idx & 63;
        tb[c][r] = (_Float16)(W[(size_t)(kt + r) * DD + nt + c] * wscale);
    }
    __syncthreads();
    for (int i = 0; i < 16; i++) {
        int idx = tid + i * 256;
        int r = idx >> 6, c = idx & 63;
        Wto[(size_t)(nt + r) * DD + kt + c] = tb[r][c];
    }
}

// ---------------- QKV projection, 128x128 tile (round-8/12 version, BK=32) ----------------
// x staged DIRECTLY from fp32 global (in-register f32->f16 convert + ds_write),
// W via gload_lds16. TOKEN-MAJOR grid (64,4,3): all 12 blocks sharing a token
// panel have the same bid%8 -> same XCD -> x L2-resident, fetched ~1x.
__global__ __launch_bounds__(256) void qkv_gemm_kernel(const float* __restrict__ x,
                                                       const _Float16* __restrict__ Wt,
                                                       const float* __restrict__ bq,
                                                       const float* __restrict__ bk,
                                                       const float* __restrict__ bv,
                                                       _Float16* __restrict__ QKV) {
    __shared__ __align__(16) _Float16 Ws[128 * 32];   // W rows (features)
    __shared__ __align__(16) _Float16 Xs[128 * 32];   // x rows (tokens)

    int which = blockIdx.z;
    const _Float16* Wtw = Wt + (size_t)which * DD * DD;
    const float* bias = (which == 0) ? bq : (which == 1) ? bk : bv;
    const float bscale = (which == 0) ? LOG2E : 1.0f;

    int tid = threadIdx.x;
    int wave = tid >> 6, lane = tid & 63;
    int quad = lane >> 4, l16 = lane & 15;
    int wm = wave >> 1, wn = wave & 1;
    int mBase = blockIdx.x * 128;   // tokens  (token-major for XCD L2 reuse)
    int nBase = blockIdx.y * 128;   // features

    int srow = wave * 32 + (lane >> 2);
    int scol = (lane & 3) * 8;
    const _Float16* wg = Wtw + (size_t)(nBase + srow) * DD + scol;
    const float*    xg = x   + (size_t)(mBase + srow) * DD + scol;
    _Float16* wl = Ws + (wave * 32) * 32;

    floatx4 acc[4][4];
    for (int i = 0; i < 4; i++)
        for (int j = 0; j < 4; j++) acc[i][j] = (floatx4){0.f, 0.f, 0.f, 0.f};

    for (int kk = 0; kk < DD; kk += 32) {
        __syncthreads();
        gload_lds16(wg + kk,           wl);
        gload_lds16(wg + 16 * DD + kk, wl + 16 * 32);
        float4 a0 = *(const float4*)(xg + kk);
        float4 a1 = *(const float4*)(xg + kk + 4);
        float4 b0 = *(const float4*)(xg + 16 * DD + kk);
        float4 b1 = *(const float4*)(xg + 16 * DD + kk + 4);
        half8 ha, hb;
        ha[0] = (_Float16)a0.x; ha[1] = (_Float16)a0.y; ha[2] = (_Float16)a0.z; ha[3] = (_Float16)a0.w;
        ha[4] = (_Float16)a1.x; ha[5] = (_Float16)a1.y; ha[6] = (_Float16)a1.z; ha[7] = (_Float16)a1.w;
        hb[0] = (_Float16)b0.x; hb[1] = (_Float16)b0.y; hb[2] = (_Float16)b0.z; hb[3] = (_Float16)b0.w;
        hb[4] = (_Float16)b1.x; hb[5] = (_Float16)b1.y; hb[6] = (_Float16)b1.z; hb[7] = (_Float16)b1.w;
        *(half8*)&Xs[srow * 32 + scol] = ha;
        *(half8*)&Xs[(srow + 16) * 32 + scol] = hb;
        __syncthreads();

        half8 af[4], bf[4];
        if (which < 2) {
            for (int i = 0; i < 4; i++)
                af[i] = *(const half8*)&Ws[(wm * 64 + i * 16 + l16) * 32 + quad * 8];
            for (int j = 0; j < 4; j++)
                bf[j] = *(const half8*)&Xs[(wn * 64 + j * 16 + l16) * 32 + quad * 8];
        } else {
            for (int i = 0; i < 4; i++)
                af[i] = *(const half8*)&Xs[(wm * 64 + i * 16 + l16) * 32 + quad * 8];
            for (int j = 0; j < 4; j++)
                bf[j] = *(const half8*)&Ws[(wn * 64 + j * 16 + l16) * 32 + quad * 8];
        }
        for (int i = 0; i < 4; i++)
            for (int j = 0; j < 4; j++)
                acc[i][j] = __builtin_amdgcn_mfma_f32_16x16x32_f16(af[i], bf[j], acc[i][j], 0, 0, 0);
    }

    if (which < 2) {
        _Float16* out = QKV + (size_t)which * (BB * NN) * DD;
        for (int i = 0; i < 4; i++) {
            int feat0 = nBase + wm * 64 + i * 16 + quad * 4;
            float4 b4 = *(const float4*)&bias[feat0];
            b4.x *= bscale; b4.y *= bscale; b4.z *= bscale; b4.w *= bscale;
            for (int j = 0; j < 4; j++) {
                int token = mBase + wn * 64 + j * 16 + l16;
                half4v pack;
                pack[0] = (_Float16)(acc[i][j][0] + b4.x);
                pack[1] = (_Float16)(acc[i][j][1] + b4.y);
                pack[2] = (_Float16)(acc[i][j][2] + b4.z);
                pack[3] = (_Float16)(acc[i][j][3] + b4.w);
                *(half4v*)&out[(size_t)token * DD + feat0] = pack;
            }
        }
    } else {
        _Float16* VT = QKV + (size_t)2 * (BB * NN) * DD;
        for (int j = 0; j < 4; j++) {
            int col = nBase + wn * 64 + j * 16 + l16;
            float bval = bias[col];
            for (int i = 0; i < 4; i++) {
                int row0 = mBase + wm * 64 + i * 16 + quad * 4;
                int b = row0 >> 10;
                int n = row0 & 1023;
                half4v pack;
                for (int reg = 0; reg < 4; reg++) pack[reg] = (_Float16)(acc[i][j][reg] + bval);
                *(half4v*)&VT[((size_t)b * 512 + col) * 1024 + n] = pack;
            }
        }
    }
}

// ---------------- flash attention — NO K/V LDS STAGING (L2-direct operands) ----------------
// Round 13: per learn_hip m169 ("LDS-staging data that L2-fits is pure overhead"),
// kf/vf are loaded DIRECTLY from global into registers. With XCD pinning each
// XCD's K+V set is 2MB (L2-resident, re-read by 16 same-XCD blocks -> L2-hot).
// Eliminates: all staging gloads, K/V LDS reads (~80% of LDS issue), and EVERY
// __syncthreads (PT is per-wave) -> 16 decorrelated waves/CU, pure TLP latency
// hiding, no barrier drains. Exp-first softmax (exp2 domain) + setprio kept.
// LDS: PT only, 8KB. grid 1024, block 256 (4 waves). Br=64, Bc=64, 16 tiles.
__global__ __launch_bounds__(256) void attn_kernel(const _Float16* __restrict__ QKV,
                                                   float* __restrict__ out) {
    const _Float16* Q  = QKV;
    const _Float16* K  = QKV + (size_t)(BB * NN) * DD;
    const _Float16* VT = QKV + (size_t)2 * (BB * NN) * DD;

    __shared__ __align__(16) _Float16 PT[4][16 * 64];   // per-wave [q][64 keys], swizzled

    int tid = threadIdx.x;
    int wave = tid >> 6, lane = tid & 63;
    int quad = lane >> 4, l16 = lane & 15;
    int l16sw = l16 & 7;
    // XCD-pinned decode: bid&7 tracks the XCD round-robin -> pin batch b per XCD.
    int bid = blockIdx.x;
    int b = bid & 7;
    int local = bid >> 3;      // 0..127 within XCD
    int h = local & 7;
    int qt = local >> 3;       // 0..15

    const _Float16* Qb  = Q + ((size_t)b * NN) * DD + h * DHH;
    const _Float16* Kb  = K + ((size_t)b * NN) * DD + h * DHH;
    const _Float16* VTb = VT + ((size_t)b * 512 + h * 64) * 1024;

    int qrow = qt * 64 + wave * 16 + l16;
    half8 qf0 = *(const half8*)(Qb + (size_t)qrow * DD + 0 * 32 + quad * 8);
    half8 qf1 = *(const half8*)(Qb + (size_t)qrow * DD + 1 * 32 + quad * 8);

    floatx4 o[4];
    for (int nt = 0; nt < 4; nt++) o[nt] = (floatx4){0.f, 0.f, 0.f, 0.f};
    float m_i = 0.0f, l_i = 0.f;   // m_i=0 init (exp-first)

    // per-lane global operand bases:
    // K row = key (stride DD), d-chunk = (ks*4+quad)*8
    const _Float16* kgl = Kb + (size_t)l16 * DD + quad * 8;
    // V row = d (stride 1024), key-chunk = (ks2*4+quad)*8
    const _Float16* vgl = VTb + (size_t)l16 * 1024 + quad * 8;

    for (int kt = 0; kt < 16; kt++) {
        // ---- QK^T (log2 domain): kf loaded L2-direct, 8 independent dwordx4 ----
        floatx4 s[4];
        for (int nt = 0; nt < 4; nt++) s[nt] = (floatx4){0.f, 0.f, 0.f, 0.f};
        __builtin_amdgcn_s_setprio(1);
        for (int ks = 0; ks < 2; ks++) {
            half8 qf = ks ? qf1 : qf0;
            for (int nt = 0; nt < 4; nt++) {
                half8 kf = *(const half8*)(kgl + (size_t)(kt * 64 + nt * 16) * DD + ks * 32);
                s[nt] = __builtin_amdgcn_mfma_f32_16x16x32_f16(kf, qf, s[nt], 0, 0, 0);
            }
        }
        __builtin_amdgcn_s_setprio(0);

        // ---- exp-first softmax: P with STALE m_i; max tree off critical path ----
        float a0 = fmaxf(fmaxf(s[0][0], s[0][1]), fmaxf(s[0][2], s[0][3]));
        float a1 = fmaxf(fmaxf(s[1][0], s[1][1]), fmaxf(s[1][2], s[1][3]));
        float a2 = fmaxf(fmaxf(s[2][0], s[2][1]), fmaxf(s[2][2], s[2][3]));
        float a3 = fmaxf(fmaxf(s[3][0], s[3][1]), fmaxf(s[3][2], s[3][3]));
        float mx = fmaxf(fmaxf(a0, a1), fmaxf(a2, a3));

        for (int nt = 0; nt < 4; nt++)
            for (int r = 0; r < 4; r++)
                s[nt][r] = EXP2F(s[nt][r] - m_i);
        float r0 = (s[0][0] + s[0][1]) + (s[0][2] + s[0][3]);
        float r1 = (s[1][0] + s[1][1]) + (s[1][2] + s[1][3]);
        float r2 = (s[2][0] + s[2][1]) + (s[2][2] + s[2][3]);
        float r3 = (s[3][0] + s[3][1]) + (s[3][2] + s[3][3]);
        float rs = (r0 + r1) + (r2 + r3);

        float mxs = __shfl_xor(mx, 16, 64);
        float rss = __shfl_xor(rs, 16, 64);
        mx = fmaxf(mx, mxs);
        rs += rss;
        mxs = __shfl_xor(mx, 32, 64);
        rss = __shfl_xor(rs, 32, 64);
        mx = fmaxf(mx, mxs);
        rs += rss;

        if (__any(mx > m_i + 11.5443f)) {
            float mnew = fmaxf(m_i, mx);
            float al = EXP2F(m_i - mnew);
            m_i = mnew;
            l_i *= al;
            rs *= al;
            for (int nt = 0; nt < 4; nt++)
                for (int r = 0; r < 4; r++) {
                    s[nt][r] *= al;
                    o[nt][r] *= al;
                }
        }
        l_i += rs;

        // ---- pack P^T tile to per-wave LDS (swizzled; no barrier needed) ----
        for (int ntl = 0; ntl < 4; ntl++) {
            half4v p4;
            for (int r = 0; r < 4; r++) p4[r] = (_Float16)s[ntl][r];
            *(half4v*)&PT[wave][l16 * 64 + (((ntl * 2 + (quad >> 1)) ^ l16sw) * 8)
                               + (quad & 1) * 4] = p4;
        }

        // ---- PV: vf loaded L2-direct ----
        __builtin_amdgcn_s_setprio(1);
        for (int ks2 = 0; ks2 < 2; ks2++) {
            half8 pf = *(const half8*)&PT[wave][l16 * 64 + (((ks2 * 4 + quad) ^ l16sw) * 8)];
            for (int nt = 0; nt < 4; nt++) {
                half8 vf = *(const half8*)(vgl + (size_t)(nt * 16) * 1024 + kt * 64 + ks2 * 32);
                o[nt] = __builtin_amdgcn_mfma_f32_16x16x32_f16(vf, pf, o[nt], 0, 0, 0);
            }
        }
        __builtin_amdgcn_s_setprio(0);
    }

    float inv = 1.0f / l_i;
    float* outb = out + ((size_t)b * NN) * DD + h * DHH;
    int row = qt * 64 + wave * 16 + l16;
    for (int nt = 0; nt < 4; nt++) {
        float4 st;
        st.x = o[nt][0] * inv; st.y = o[nt][1] * inv;
        st.z = o[nt][2] * inv; st.w = o[nt][3] * inv;
        *(float4*)&outb[(size_t)row * DD + nt * 16 + quad * 4] = st;
    }
}

extern "C" void kernel_launch(void* const* d_in, const int* in_sizes, int n_in,
                              void* d_out, int out_size, void* d_ws, size_t ws_size,
                              hipStream_t stream) {
    const float* x  = (const float*)d_in[0];
    const float* Wq = (const float*)d_in[1];
    const float* bq = (const float*)d_in[2];
    const float* Wk = (const float*)d_in[3];
    const float* bk = (const float*)d_in[4];
    const float* Wv = (const float*)d_in[5];
    const float* bv = (const float*)d_in[6];
    float* out = (float*)d_out;

    _Float16* Wt  = (_Float16*)d_ws;
    _Float16* QKV = Wt + (size_t)3 * DD * DD;

    hipLaunchKernelGGL(cvt_kernel, dim3(192), dim3(256), 0, stream,
                       Wq, Wk, Wv, Wt);
    hipLaunchKernelGGL(qkv_gemm_kernel, dim3(64, 4, 3), dim3(256), 0, stream,
                       x, Wt, bq, bk, bv, QKV);
    hipLaunchKernelGGL(attn_kernel, dim3(1024), dim3(256), 0, stream, QKV, out);
}

// Round 14
// 134.234 us; speedup vs baseline: 1.6232x; 1.6232x over previous
//
#include <hip/hip_runtime.h>
#include <hip/hip_bf16.h>

typedef _Float16 half8 __attribute__((ext_vector_type(8)));
typedef _Float16 half4v __attribute__((ext_vector_type(4)));
typedef __fp16 fp16x2 __attribute__((ext_vector_type(2)));   // cvt_pkrtz return type
typedef float floatx4 __attribute__((ext_vector_type(4)));
typedef float floatx16 __attribute__((ext_vector_type(16)));

// Problem constants: B=8, N=1024, D=512, H=8, DH=64
#define BB 8
#define NN 1024
#define DD 512
#define HH 8
#define DHH 64
#define LOG2E 1.4426950408889634f

// hardware 2^x (v_exp_f32)
#define EXP2F(x) __builtin_amdgcn_exp2f(x)

// async global->LDS, 16B per lane, dest = wave-uniform base + lane*16
__device__ __forceinline__ void gload_lds16(const _Float16* g, _Float16* l) {
    __builtin_amdgcn_global_load_lds(
        (const __attribute__((address_space(1))) void*)g,
        (__attribute__((address_space(3))) void*)l, 16, 0, 0);
}

// ---------------- W fp32->fp16 transpose only (round-8 version) ----------------
__global__ __launch_bounds__(256) void cvt_kernel(const float* __restrict__ Wq,
                                                  const float* __restrict__ Wk,
                                                  const float* __restrict__ Wv,
                                                  _Float16* __restrict__ Wt) {
    __shared__ __align__(16) _Float16 tb[64][72];
    int t = blockIdx.x;                // 0..191
    int tid = threadIdx.x;
    int which = t >> 6;                // /64
    int rem = t & 63;
    int kt = (rem >> 3) * 64, nt = (rem & 7) * 64;
    const float* W = (which == 0) ? Wq : (which == 1) ? Wk : Wv;
    float wscale = (which == 0) ? LOG2E : 1.0f;
    _Float16* Wto = Wt + (size_t)which * DD * DD;
    for (int i = 0; i < 16; i++) {
        int idx = tid + i * 256;
        int r = idx >> 6, c = idx & 63;
        tb[c][r] = (_Float16)(W[(size_t)(kt + r) * DD + nt + c] * wscale);
    }
    __syncthreads();
    for (int i = 0; i < 16; i++) {
        int idx = tid + i * 256;
        int r = idx >> 6, c = idx & 63;
        Wto[(size_t)(nt + r) * DD + kt + c] = tb[r][c];
    }
}

// ---------------- QKV projection, 128x128 tile (round-8/12 version, BK=32) ----------------
__global__ __launch_bounds__(256) void qkv_gemm_kernel(const float* __restrict__ x,
                                                       const _Float16* __restrict__ Wt,
                                                       const float* __restrict__ bq,
                                                       const float* __restrict__ bk,
                                                       const float* __restrict__ bv,
                                                       _Float16* __restrict__ QKV) {
    __shared__ __align__(16) _Float16 Ws[128 * 32];   // W rows (features)
    __shared__ __align__(16) _Float16 Xs[128 * 32];   // x rows (tokens)

    int which = blockIdx.z;
    const _Float16* Wtw = Wt + (size_t)which * DD * DD;
    const float* bias = (which == 0) ? bq : (which == 1) ? bk : bv;
    const float bscale = (which == 0) ? LOG2E : 1.0f;

    int tid = threadIdx.x;
    int wave = tid >> 6, lane = tid & 63;
    int quad = lane >> 4, l16 = lane & 15;
    int wm = wave >> 1, wn = wave & 1;
    int mBase = blockIdx.x * 128;   // tokens  (token-major for XCD L2 reuse)
    int nBase = blockIdx.y * 128;   // features

    int srow = wave * 32 + (lane >> 2);
    int scol = (lane & 3) * 8;
    const _Float16* wg = Wtw + (size_t)(nBase + srow) * DD + scol;
    const float*    xg = x   + (size_t)(mBase + srow) * DD + scol;
    _Float16* wl = Ws + (wave * 32) * 32;

    floatx4 acc[4][4];
    for (int i = 0; i < 4; i++)
        for (int j = 0; j < 4; j++) acc[i][j] = (floatx4){0.f, 0.f, 0.f, 0.f};

    for (int kk = 0; kk < DD; kk += 32) {
        __syncthreads();
        gload_lds16(wg + kk,           wl);
        gload_lds16(wg + 16 * DD + kk, wl + 16 * 32);
        float4 a0 = *(const float4*)(xg + kk);
        float4 a1 = *(const float4*)(xg + kk + 4);
        float4 b0 = *(const float4*)(xg + 16 * DD + kk);
        float4 b1 = *(const float4*)(xg + 16 * DD + kk + 4);
        half8 ha, hb;
        ha[0] = (_Float16)a0.x; ha[1] = (_Float16)a0.y; ha[2] = (_Float16)a0.z; ha[3] = (_Float16)a0.w;
        ha[4] = (_Float16)a1.x; ha[5] = (_Float16)a1.y; ha[6] = (_Float16)a1.z; ha[7] = (_Float16)a1.w;
        hb[0] = (_Float16)b0.x; hb[1] = (_Float16)b0.y; hb[2] = (_Float16)b0.z; hb[3] = (_Float16)b0.w;
        hb[4] = (_Float16)b1.x; hb[5] = (_Float16)b1.y; hb[6] = (_Float16)b1.z; hb[7] = (_Float16)b1.w;
        *(half8*)&Xs[srow * 32 + scol] = ha;
        *(half8*)&Xs[(srow + 16) * 32 + scol] = hb;
        __syncthreads();

        half8 af[4], bf[4];
        if (which < 2) {
            for (int i = 0; i < 4; i++)
                af[i] = *(const half8*)&Ws[(wm * 64 + i * 16 + l16) * 32 + quad * 8];
            for (int j = 0; j < 4; j++)
                bf[j] = *(const half8*)&Xs[(wn * 64 + j * 16 + l16) * 32 + quad * 8];
        } else {
            for (int i = 0; i < 4; i++)
                af[i] = *(const half8*)&Xs[(wm * 64 + i * 16 + l16) * 32 + quad * 8];
            for (int j = 0; j < 4; j++)
                bf[j] = *(const half8*)&Ws[(wn * 64 + j * 16 + l16) * 32 + quad * 8];
        }
        for (int i = 0; i < 4; i++)
            for (int j = 0; j < 4; j++)
                acc[i][j] = __builtin_amdgcn_mfma_f32_16x16x32_f16(af[i], bf[j], acc[i][j], 0, 0, 0);
    }

    if (which < 2) {
        _Float16* out = QKV + (size_t)which * (BB * NN) * DD;
        for (int i = 0; i < 4; i++) {
            int feat0 = nBase + wm * 64 + i * 16 + quad * 4;
            float4 b4 = *(const float4*)&bias[feat0];
            b4.x *= bscale; b4.y *= bscale; b4.z *= bscale; b4.w *= bscale;
            for (int j = 0; j < 4; j++) {
                int token = mBase + wn * 64 + j * 16 + l16;
                half4v pack;
                pack[0] = (_Float16)(acc[i][j][0] + b4.x);
                pack[1] = (_Float16)(acc[i][j][1] + b4.y);
                pack[2] = (_Float16)(acc[i][j][2] + b4.z);
                pack[3] = (_Float16)(acc[i][j][3] + b4.w);
                *(half4v*)&out[(size_t)token * DD + feat0] = pack;
            }
        }
    } else {
        _Float16* VT = QKV + (size_t)2 * (BB * NN) * DD;
        for (int j = 0; j < 4; j++) {
            int col = nBase + wn * 64 + j * 16 + l16;
            float bval = bias[col];
            for (int i = 0; i < 4; i++) {
                int row0 = mBase + wm * 64 + i * 16 + quad * 4;
                int b = row0 >> 10;
                int n = row0 & 1023;
                half4v pack;
                for (int reg = 0; reg < 4; reg++) pack[reg] = (_Float16)(acc[i][j][reg] + bval);
                *(half4v*)&VT[((size_t)b * 512 + col) * 1024 + n] = pack;
            }
        }
    }
}

// ---------------- flash attention, 32x32 MFMA, 2-wave blocks ----------------
// Round 14: v_mfma_f32_32x32x16_f16 — each wave computes 32 q x 64 keys per
// tile from the SAME LDS reads (2x FLOP/LDS-byte vs 16x16); grid stays 1024
// (4 blocks/CU). P never touches LDS: the 32x32 C-layout (col=lane&31,
// row=(r&3)+8(r>>2)+4(lane>>5), HW-verified) feeds PV's B-operand directly
// after cvt_pkrtz, with V's A-frags read in the matching permuted key order
// (two ds_read_b64 at key base +4*hf and +8). Softmax cross-reduce = one
// shfl_xor(32). Exp-first softmax (exp2 domain), dbuf K/V (one barrier/tile),
// XCD-pinned mapping, s_setprio.
// LDS: Kt 2x8KB + Vt 2x8KB = 32KB. block 128 (2 waves), grid 1024.
__global__ __launch_bounds__(128) void attn_kernel(const _Float16* __restrict__ QKV,
                                                   float* __restrict__ out) {
    const _Float16* Q  = QKV;
    const _Float16* K  = QKV + (size_t)(BB * NN) * DD;
    const _Float16* VT = QKV + (size_t)2 * (BB * NN) * DD;

    __shared__ __align__(16) _Float16 Kt[2][64 * 64];   // [key][d], XOR-swizzled chunks
    __shared__ __align__(16) _Float16 Vt[2][64 * 64];   // [d][key], XOR-swizzled chunks

    int tid = threadIdx.x;
    int wave = tid >> 6, lane = tid & 63;
    int l31 = lane & 31, hf = lane >> 5;
    int xr = l31 & 7;
    // XCD-pinned decode: bid&7 = batch b per XCD.
    int bid = blockIdx.x;
    int b = bid & 7;
    int local = bid >> 3;      // 0..127
    int h = local & 7;
    int qt = local >> 3;       // 0..15

    const _Float16* Qb  = Q + ((size_t)b * NN) * DD + h * DHH;
    const _Float16* Kb  = K + ((size_t)b * NN) * DD + h * DHH;
    const _Float16* VTb = VT + ((size_t)b * 512 + h * 64) * 1024;

    // Q B-frags: col=lane&31=q, k=(lane>>5)*8+reg over d; 4 slices of 16 d.
    int qrow = qt * 64 + wave * 32 + l31;
    half8 qf[4];
    for (int sl = 0; sl < 4; sl++)
        qf[sl] = *(const half8*)(Qb + (size_t)qrow * DD + sl * 16 + hf * 8);

    floatx16 o0, o1;
    for (int i = 0; i < 16; i++) { o0[i] = 0.f; o1[i] = 0.f; }
    float m_i = 0.0f, l_i = 0.f;   // exp-first: m init 0

    // staging (pre-swizzled global src, linear LDS dest); wave w covers rows w*32..+31
    int srow = lane >> 3;
    int schunk = (lane & 7) ^ srow;
    const _Float16* kg = Kb + (size_t)(wave * 32 + srow) * DD + schunk * 8;
    const _Float16* vg = VTb + (size_t)(wave * 32 + srow) * 1024 + schunk * 8;
    _Float16* kl0 = &Kt[0][(wave * 32) * 64];
    _Float16* vl0 = &Vt[0][(wave * 32) * 64];
    _Float16* kl1 = &Kt[1][(wave * 32) * 64];
    _Float16* vl1 = &Vt[1][(wave * 32) * 64];

    auto STAGE = [&](int kt, _Float16* kl, _Float16* vl) {
        for (int j = 0; j < 4; j++) {
            gload_lds16(kg + (size_t)(kt * 64 + j * 8) * DD, kl + (j * 8) * 64);
            gload_lds16(vg + (size_t)(j * 8) * 1024 + kt * 64, vl + (j * 8) * 64);
        }
    };

    STAGE(0, kl0, vl0);

    for (int kt = 0; kt < 16; kt++) {
        int cur = kt & 1;
        __syncthreads();
        if (kt + 1 < 16)
            STAGE(kt + 1, cur ? kl0 : kl1, cur ? vl0 : vl1);

        const _Float16* Kc = cur ? &Kt[1][0] : &Kt[0][0];
        const _Float16* Vc = cur ? &Vt[1][0] : &Vt[0][0];

        // ---- QK^T: S^T[key][q], two 32-key subtiles, K=16 slices over d ----
        floatx16 s0, s1;
        for (int i = 0; i < 16; i++) { s0[i] = 0.f; s1[i] = 0.f; }
        __builtin_amdgcn_s_setprio(1);
        for (int sl = 0; sl < 4; sl++) {
            int c = sl * 2 + hf;
            half8 kf0 = *(const half8*)&Kc[l31 * 64 + ((c ^ xr) * 8)];
            half8 kf1 = *(const half8*)&Kc[(32 + l31) * 64 + ((c ^ xr) * 8)];
            s0 = __builtin_amdgcn_mfma_f32_32x32x16_f16(kf0, qf[sl], s0, 0, 0, 0);
            s1 = __builtin_amdgcn_mfma_f32_32x32x16_f16(kf1, qf[sl], s1, 0, 0, 0);
        }
        __builtin_amdgcn_s_setprio(0);

        // ---- exp-first softmax (stale m), max off critical path ----
        float mx = s0[0];
        for (int i = 1; i < 16; i++) mx = fmaxf(mx, s0[i]);
        for (int i = 0; i < 16; i++) mx = fmaxf(mx, s1[i]);

        for (int i = 0; i < 16; i++) s0[i] = EXP2F(s0[i] - m_i);
        for (int i = 0; i < 16; i++) s1[i] = EXP2F(s1[i] - m_i);
        float rs = 0.f;
        for (int i = 0; i < 16; i++) rs += s0[i];
        for (int i = 0; i < 16; i++) rs += s1[i];

        mx = fmaxf(mx, __shfl_xor(mx, 32, 64));
        rs += __shfl_xor(rs, 32, 64);

        if (__any(mx > m_i + 11.5443f)) {
            float mnew = fmaxf(m_i, mx);
            float al = EXP2F(m_i - mnew);
            m_i = mnew;
            l_i *= al;
            rs *= al;
            for (int i = 0; i < 16; i++) {
                s0[i] *= al; s1[i] *= al;
                o0[i] *= al; o1[i] *= al;
            }
        }
        l_i += rs;

        // ---- PV: o^T[d][q] += V^T[d][k] x P[k][q], P direct from C-layout ----
        // B-frag for (sub,h16): pack S regs h16*8..+7 (keys in C-order); A (V)
        // reads the SAME key order: b64 at key sub*32+h16*16+4*hf and +8.
        __builtin_amdgcn_s_setprio(1);
        {
            // sub = 0 (keys 0..31) from s0; sub = 1 (keys 32..63) from s1
            for (int sub = 0; sub < 2; sub++) {
                const floatx16& S = sub ? s1 : s0;
                for (int h16 = 0; h16 < 2; h16++) {
                    fp16x2 p0 = __builtin_amdgcn_cvt_pkrtz(S[h16 * 8 + 0], S[h16 * 8 + 1]);
                    fp16x2 p1 = __builtin_amdgcn_cvt_pkrtz(S[h16 * 8 + 2], S[h16 * 8 + 3]);
                    fp16x2 p2 = __builtin_amdgcn_cvt_pkrtz(S[h16 * 8 + 4], S[h16 * 8 + 5]);
                    fp16x2 p3 = __builtin_amdgcn_cvt_pkrtz(S[h16 * 8 + 6], S[h16 * 8 + 7]);
                    half8 pf;
                    pf[0] = (_Float16)p0[0]; pf[1] = (_Float16)p0[1];
                    pf[2] = (_Float16)p1[0]; pf[3] = (_Float16)p1[1];
                    pf[4] = (_Float16)p2[0]; pf[5] = (_Float16)p2[1];
                    pf[6] = (_Float16)p3[0]; pf[7] = (_Float16)p3[1];
                    int c1 = sub * 4 + h16 * 2;
                    // dsub = 0
                    {
                        const _Float16* base = &Vc[l31 * 64];
                        half4v v0 = *(const half4v*)(base + ((c1 ^ xr) * 8) + 4 * hf);
                        half4v v1 = *(const half4v*)(base + (((c1 + 1) ^ xr) * 8) + 4 * hf);
                        half8 vf;
                        vf[0] = v0[0]; vf[1] = v0[1]; vf[2] = v0[2]; vf[3] = v0[3];
                        vf[4] = v1[0]; vf[5] = v1[1]; vf[6] = v1[2]; vf[7] = v1[3];
                        o0 = __builtin_amdgcn_mfma_f32_32x32x16_f16(vf, pf, o0, 0, 0, 0);
                    }
                    // dsub = 1
                    {
                        const _Float16* base = &Vc[(32 + l31) * 64];
                        half4v v0 = *(const half4v*)(base + ((c1 ^ xr) * 8) + 4 * hf);
                        half4v v1 = *(const half4v*)(base + (((c1 + 1) ^ xr) * 8) + 4 * hf);
                        half8 vf;
                        vf[0] = v0[0]; vf[1] = v0[1]; vf[2] = v0[2]; vf[3] = v0[3];
                        vf[4] = v1[0]; vf[5] = v1[1]; vf[6] = v1[2]; vf[7] = v1[3];
                        o1 = __builtin_amdgcn_mfma_f32_32x32x16_f16(vf, pf, o1, 0, 0, 0);
                    }
                }
            }
        }
        __builtin_amdgcn_s_setprio(0);
    }

    // ---- store: O^T C-layout col=q=lane&31, row d = (r&3)+8*(r>>2)+4*hf (+dsub*32) ----
    float inv = 1.0f / l_i;
    float* outb = out + ((size_t)b * NN) * DD + h * DHH;
    for (int g = 0; g < 4; g++) {
        float4 st;
        st.x = o0[g * 4 + 0] * inv; st.y = o0[g * 4 + 1] * inv;
        st.z = o0[g * 4 + 2] * inv; st.w = o0[g * 4 + 3] * inv;
        *(float4*)&outb[(size_t)qrow * DD + g * 8 + 4 * hf] = st;
    }
    for (int g = 0; g < 4; g++) {
        float4 st;
        st.x = o1[g * 4 + 0] * inv; st.y = o1[g * 4 + 1] * inv;
        st.z = o1[g * 4 + 2] * inv; st.w = o1[g * 4 + 3] * inv;
        *(float4*)&outb[(size_t)qrow * DD + 32 + g * 8 + 4 * hf] = st;
    }
}

extern "C" void kernel_launch(void* const* d_in, const int* in_sizes, int n_in,
                              void* d_out, int out_size, void* d_ws, size_t ws_size,
                              hipStream_t stream) {
    const float* x  = (const float*)d_in[0];
    const float* Wq = (const float*)d_in[1];
    const float* bq = (const float*)d_in[2];
    const float* Wk = (const float*)d_in[3];
    const float* bk = (const float*)d_in[4];
    const float* Wv = (const float*)d_in[5];
    const float* bv = (const float*)d_in[6];
    float* out = (float*)d_out;

    _Float16* Wt  = (_Float16*)d_ws;
    _Float16* QKV = Wt + (size_t)3 * DD * DD;

    hipLaunchKernelGGL(cvt_kernel, dim3(192), dim3(256), 0, stream,
                       Wq, Wk, Wv, Wt);
    hipLaunchKernelGGL(qkv_gemm_kernel, dim3(64, 4, 3), dim3(256), 0, stream,
                       x, Wt, bq, bk, bv, QKV);
    hipLaunchKernelGGL(attn_kernel, dim3(1024), dim3(128), 0, stream, QKV, out);
}